// Round 5
// baseline (192.703 us; speedup 1.0000x reference)
//
#include <hip/hip_runtime.h>

#define B_  8
#define TQ  256
#define TV  512
#define DD  256

__device__ __forceinline__ float fast_exp2(float x) {
#if __has_builtin(__builtin_amdgcn_exp2f)
  return __builtin_amdgcn_exp2f(x);
#else
  return __exp2f(x);
#endif
}
__device__ __forceinline__ float fast_rcp(float x) {
#if __has_builtin(__builtin_amdgcn_rcpf)
  return __builtin_amdgcn_rcpf(x);
#else
  return 1.0f / x;
#endif
}

// ---------------------------------------------------------------------------
// Fused projections with EXP epilogue:
//   Eq = exp2(SC*(query@W1 + b1)),  Ev = exp2(SC*(value@W2 + b2))
// so the attention inner loop needs zero exp2 (exp2(c(q+v)) = Eq*Ev).
// BM=32, BN=64, BK=64, 256 thr, 2x4 microtile -> 768 blocks (3 blocks/CU).
// Plain ld/st staging only (no async); all LDS patterns 2-way/phase = free.
// ---------------------------------------------------------------------------
__global__ __launch_bounds__(256) void proj_fused(
    const float* __restrict__ query, const float* __restrict__ value,
    const float* __restrict__ W1, const float* __restrict__ b1,
    const float* __restrict__ W2, const float* __restrict__ b2,
    float* __restrict__ qp, float* __restrict__ vp, float scale) {
  __shared__ float As[64][33];  // As[k][m], +1 pad
  __shared__ float Bs[64][64];  // Bs[k][n]
  const int t  = threadIdx.x;
  const int rt = blockIdx.x;
  const int bn = blockIdx.y * 64;

  const float* A; const float* W; const float* bias; float* out; int row0;
  if (rt < 64) { row0 = rt * 32;        A = query; W = W1; bias = b1; out = qp; }
  else         { row0 = (rt - 64) * 32; A = value; W = W2; bias = b2; out = vp; }

  const int tx = t & 15, ty = t >> 4;
  const int arow = t >> 3, acol = (t & 7) << 3;   // A stage: 8 floats/thread

  float acc[2][4] = {{0.f,0.f,0.f,0.f},{0.f,0.f,0.f,0.f}};

  for (int k0 = 0; k0 < 256; k0 += 64) {
    float4 a0 = *(const float4*)(A + (size_t)(row0 + arow) * DD + k0 + acol);
    float4 a1 = *(const float4*)(A + (size_t)(row0 + arow) * DD + k0 + acol + 4);
    As[acol + 0][arow] = a0.x; As[acol + 1][arow] = a0.y;
    As[acol + 2][arow] = a0.z; As[acol + 3][arow] = a0.w;
    As[acol + 4][arow] = a1.x; As[acol + 5][arow] = a1.y;
    As[acol + 6][arow] = a1.z; As[acol + 7][arow] = a1.w;
    // B stage: float4 id = k*256 + t -> (row = id>>4, col4 = id&15);
    // 16 lanes cover one 64-float row contiguously (coalesced 256B).
#pragma unroll
    for (int k = 0; k < 4; ++k) {
      const int id = (k << 8) + t;
      const int row = id >> 4, col4 = (id & 15) << 2;
      *(float4*)&Bs[row][col4] =
          *(const float4*)(W + (size_t)(k0 + row) * DD + bn + col4);
    }
    __syncthreads();
#pragma unroll 16
    for (int k = 0; k < 64; ++k) {
      float2 av = *(const float2*)&As[k][ty << 1];
      float4 bv = *(const float4*)&Bs[k][tx << 2];
      acc[0][0] = fmaf(av.x, bv.x, acc[0][0]); acc[0][1] = fmaf(av.x, bv.y, acc[0][1]);
      acc[0][2] = fmaf(av.x, bv.z, acc[0][2]); acc[0][3] = fmaf(av.x, bv.w, acc[0][3]);
      acc[1][0] = fmaf(av.y, bv.x, acc[1][0]); acc[1][1] = fmaf(av.y, bv.y, acc[1][1]);
      acc[1][2] = fmaf(av.y, bv.z, acc[1][2]); acc[1][3] = fmaf(av.y, bv.w, acc[1][3]);
    }
    __syncthreads();
  }

  float4 bvv = *(const float4*)&bias[bn + (tx << 2)];
#pragma unroll
  for (int r = 0; r < 2; ++r) {
    float4 o;
    o.x = fast_exp2(scale * (acc[r][0] + bvv.x));
    o.y = fast_exp2(scale * (acc[r][1] + bvv.y));
    o.z = fast_exp2(scale * (acc[r][2] + bvv.z));
    o.w = fast_exp2(scale * (acc[r][3] + bvv.w));
    *(float4*)(out + (size_t)(row0 + (ty << 1) + r) * DD + bn + (tx << 2)) = o;
  }
}

// ---------------------------------------------------------------------------
// Fused score + softmax + context + concat + transposed alignment.
// 512 blocks x 512 threads (8 waves), LDS 78848 B -> 2 blocks/CU.
// Wave wv = (rr = wv&3 -> q-row, hh = wv>>2 -> j-half of chunk).
// Lane = (dh = lane>>5 -> d-half, jj = lane&31 -> j). One in-register
// shfl_xor(32) combines d-halves; no LDS aliasing, no async copies,
// no cross-wave shared-location read/write except through __syncthreads.
// Inner math (inputs Eq, Ev; a = Eq*Ev = exp(2(q+v))):
//   tanh(q+v) = 1 - 2/(1+a);  1/(1+a)+1/(1+b) = (2+a+b)/(1+a+b+ab)
// -> per float4: 12 VALU + 2 rcp, zero exp2.
// score = 256 - 2*S,  S = sum_d 1/(1+a_d);  softmax via min-S trick.
// ---------------------------------------------------------------------------
__global__ __launch_bounds__(512, 4) void attn_kernel(
    const float* __restrict__ qp, const float* __restrict__ vp,
    const float* __restrict__ value, const float* __restrict__ query,
    float* __restrict__ out1, float* __restrict__ out2) {
  __shared__ float vs[64][260];   // Ev chunk (stride 260 -> 2-way/phase, free)
  __shared__ float qsh[4][256];   // 4 Eq rows (broadcast reads)
  __shared__ float alg[4][512];   // raw S, then normalized alignment

  const int t    = threadIdx.x;
  const int lane = t & 63;
  const int wv   = t >> 6;        // 0..7
  const int rr   = wv & 3;        // q-row within block
  const int hh   = wv >> 2;       // j-half of chunk
  const int jj   = lane & 31;     // j within half-chunk
  const int dh   = lane >> 5;     // d-half
  const int bb   = blockIdx.x & 7;          // batch -> XCD locality
  const int i0   = (blockIdx.x >> 3) << 2;  // first q-row of this block

  // stage 4 Eq rows (plain ld/st)
  if (t < 256) {
    const int qr = t >> 6, qc = (t & 63) << 2;
    *(float4*)&qsh[qr][qc] =
        *(const float4*)(qp + (size_t)(bb * TQ + i0 + qr) * DD + qc);
  }

  const float* vpb = vp + (size_t)bb * TV * DD;
  const int srow = t >> 6;          // staging row base 0..7
  const int scol = (t & 63) << 2;   // staging col (coalesced 16 B/lane)

  // prefetch chunk 0 into registers
  float4 pre[8];
#pragma unroll
  for (int k = 0; k < 8; ++k)
    pre[k] = *(const float4*)(vpb + (size_t)((k << 3) + srow) * DD + scol);

  for (int c = 0; c < 8; ++c) {
#pragma unroll
    for (int k = 0; k < 8; ++k)
      *(float4*)&vs[(k << 3) + srow][scol] = pre[k];
    __syncthreads();

    if (c < 7) {  // prefetch next chunk while computing this one
#pragma unroll
      for (int k = 0; k < 8; ++k)
        pre[k] = *(const float4*)(vpb + (size_t)(((c + 1) << 6) + (k << 3) + srow) * DD + scol);
    }

    float acc0 = 0.f, acc1 = 0.f;
    const float* qrow = &qsh[rr][dh << 7];
    const float* vrow = &vs[(hh << 5) + jj][dh << 7];
#pragma unroll 8
    for (int d4 = 0; d4 < 32; ++d4) {
      float4 q4 = *(const float4*)&qrow[d4 << 2];
      float4 v4 = *(const float4*)&vrow[d4 << 2];
      float a0 = q4.x * v4.x, a1 = q4.y * v4.y;
      float a2 = q4.z * v4.z, a3 = q4.w * v4.w;
      float s01 = a0 + a1,   s23 = a2 + a3;
      float d01 = fmaf(a0, a1, s01 + 1.f);
      float d23 = fmaf(a2, a3, s23 + 1.f);
      acc0 = fmaf(s01 + 2.f, fast_rcp(d01), acc0);
      acc1 = fmaf(s23 + 2.f, fast_rcp(d23), acc1);
    }
    float acc = acc0 + acc1;
    acc += __shfl_xor(acc, 32, 64);           // combine d-halves in-register
    if (dh == 0) alg[rr][(c << 6) + (hh << 5) + jj] = acc;
    __syncthreads();  // alg complete + protect vs before next chunk store
  }

  // ---- softmax over j: wave wv (<4) owns row wv exclusively ----
  // score = 256 - 2*S -> max(score) <-> min(S); w = exp2(CC*(Smin - S))
  if (wv < 4) {
    float s[8];
#pragma unroll
    for (int c = 0; c < 8; ++c) s[c] = alg[wv][(c << 6) + lane];
    float mn = s[0];
#pragma unroll
    for (int c = 1; c < 8; ++c) mn = fminf(mn, s[c]);
#pragma unroll
    for (int m = 1; m < 64; m <<= 1) mn = fminf(mn, __shfl_xor(mn, m, 64));

    const float CC = 2.8853900817779268f;  // 2*log2(e)
    float p[8];
    float sum = 0.f;
#pragma unroll
    for (int c = 0; c < 8; ++c) { p[c] = fast_exp2(CC * (mn - s[c])); sum += p[c]; }
#pragma unroll
    for (int m = 1; m < 64; m <<= 1) sum += __shfl_xor(sum, m, 64);
    const float inv = fast_rcp(sum);
#pragma unroll
    for (int c = 0; c < 8; ++c) alg[wv][(c << 6) + lane] = p[c] * inv;
  }
  __syncthreads();

  // ---- alignment_t write: out2[b][j][i0..i0+3], one float4 per thread ----
  {
    const int j = t;  // 0..511
    float4 av = make_float4(alg[0][j], alg[1][j], alg[2][j], alg[3][j]);
    *(float4*)(out2 + (size_t)(bb * TV + j) * TQ + i0) = av;
  }

  // ---- context: thread t owns (feature f, row-pair rp) ----
  const int f  = t & 255;
  const int rp = t >> 8;          // 0 or 1 -> rows 2rp, 2rp+1
  float c0 = 0.f, c1 = 0.f;
  const float* vb = value + (size_t)bb * TV * DD;
  const float* a0p = &alg[(rp << 1) + 0][0];
  const float* a1p = &alg[(rp << 1) + 1][0];
#pragma unroll 2
  for (int j = 0; j < TV; j += 4) {
    float v0 = vb[(size_t)(j + 0) * DD + f];
    float v1 = vb[(size_t)(j + 1) * DD + f];
    float v2 = vb[(size_t)(j + 2) * DD + f];
    float v3 = vb[(size_t)(j + 3) * DD + f];
    float4 a0 = *(const float4*)&a0p[j];
    float4 a1 = *(const float4*)&a1p[j];
    c0 += a0.x * v0 + a0.y * v1 + a0.z * v2 + a0.w * v3;
    c1 += a1.x * v0 + a1.y * v1 + a1.z * v2 + a1.w * v3;
  }

  // ---- context-concat output: [ctx | query] per row ----
  const int r0 = (rp << 1), r1 = r0 + 1;
  const float* qg = query + (size_t)(bb * TQ + i0) * DD;
  float* o = out1 + (size_t)(bb * TQ + i0) * (2 * DD);
  o[r0 * 512 + f] = c0; o[r0 * 512 + 256 + f] = qg[r0 * DD + f];
  o[r1 * 512 + f] = c1; o[r1 * 512 + 256 + f] = qg[r1 * DD + f];
}

// ---------------------------------------------------------------------------
extern "C" void kernel_launch(void* const* d_in, const int* in_sizes, int n_in,
                              void* d_out, int out_size, void* d_ws, size_t ws_size,
                              hipStream_t stream) {
  const float* query = (const float*)d_in[0];  // [8,256,256]
  const float* value = (const float*)d_in[1];  // [8,512,256]
  const float* W1    = (const float*)d_in[2];  // [256,256]
  const float* b1    = (const float*)d_in[3];  // [256]
  const float* W2    = (const float*)d_in[4];  // [256,256]
  const float* b2    = (const float*)d_in[5];  // [256]

  float* out1 = (float*)d_out;                     // context concat [8,256,512]
  float* out2 = out1 + (size_t)B_ * TQ * 2 * DD;   // alignment_t   [8,512,256]

  float* qp = (float*)d_ws;                        // Eq: 2048*256 floats
  float* vp = qp + (size_t)B_ * TQ * DD;           // Ev: 4096*256 floats

  const float SC = 2.8853900817779268f;  // 2*log2(e): exp(2x) = exp2(SC*x)

  proj_fused<<<dim3(192, 4), 256, 0, stream>>>(query, value, W1, b1, W2, b2, qp, vp, SC);
  attn_kernel<<<dim3(B_ * (TQ / 4)), 512, 0, stream>>>(qp, vp, value, query, out1, out2);
}

// Round 6
// 187.915 us; speedup vs baseline: 1.0255x; 1.0255x over previous
//
#include <hip/hip_runtime.h>

#define B_  8
#define TQ  256
#define TV  512
#define DD  256

__device__ __forceinline__ float fast_exp2(float x) {
#if __has_builtin(__builtin_amdgcn_exp2f)
  return __builtin_amdgcn_exp2f(x);
#else
  return __exp2f(x);
#endif
}
__device__ __forceinline__ float fast_rcp(float x) {
#if __has_builtin(__builtin_amdgcn_rcpf)
  return __builtin_amdgcn_rcpf(x);
#else
  return 1.0f / x;
#endif
}

// ---------------------------------------------------------------------------
// Fused projections with EXP epilogue:
//   Eq = exp2(SC*(query@W1 + b1)),  Ev = exp2(SC*(value@W2 + b2))
// (unchanged from round 5 — passed validation)
// ---------------------------------------------------------------------------
__global__ __launch_bounds__(256) void proj_fused(
    const float* __restrict__ query, const float* __restrict__ value,
    const float* __restrict__ W1, const float* __restrict__ b1,
    const float* __restrict__ W2, const float* __restrict__ b2,
    float* __restrict__ qp, float* __restrict__ vp, float scale) {
  __shared__ float As[64][33];  // As[k][m], +1 pad
  __shared__ float Bs[64][64];  // Bs[k][n]
  const int t  = threadIdx.x;
  const int rt = blockIdx.x;
  const int bn = blockIdx.y * 64;

  const float* A; const float* W; const float* bias; float* out; int row0;
  if (rt < 64) { row0 = rt * 32;        A = query; W = W1; bias = b1; out = qp; }
  else         { row0 = (rt - 64) * 32; A = value; W = W2; bias = b2; out = vp; }

  const int tx = t & 15, ty = t >> 4;
  const int arow = t >> 3, acol = (t & 7) << 3;

  float acc[2][4] = {{0.f,0.f,0.f,0.f},{0.f,0.f,0.f,0.f}};

  for (int k0 = 0; k0 < 256; k0 += 64) {
    float4 a0 = *(const float4*)(A + (size_t)(row0 + arow) * DD + k0 + acol);
    float4 a1 = *(const float4*)(A + (size_t)(row0 + arow) * DD + k0 + acol + 4);
    As[acol + 0][arow] = a0.x; As[acol + 1][arow] = a0.y;
    As[acol + 2][arow] = a0.z; As[acol + 3][arow] = a0.w;
    As[acol + 4][arow] = a1.x; As[acol + 5][arow] = a1.y;
    As[acol + 6][arow] = a1.z; As[acol + 7][arow] = a1.w;
#pragma unroll
    for (int k = 0; k < 4; ++k) {
      const int id = (k << 8) + t;
      const int row = id >> 4, col4 = (id & 15) << 2;
      *(float4*)&Bs[row][col4] =
          *(const float4*)(W + (size_t)(k0 + row) * DD + bn + col4);
    }
    __syncthreads();
#pragma unroll 16
    for (int k = 0; k < 64; ++k) {
      float2 av = *(const float2*)&As[k][ty << 1];
      float4 bv = *(const float4*)&Bs[k][tx << 2];
      acc[0][0] = fmaf(av.x, bv.x, acc[0][0]); acc[0][1] = fmaf(av.x, bv.y, acc[0][1]);
      acc[0][2] = fmaf(av.x, bv.z, acc[0][2]); acc[0][3] = fmaf(av.x, bv.w, acc[0][3]);
      acc[1][0] = fmaf(av.y, bv.x, acc[1][0]); acc[1][1] = fmaf(av.y, bv.y, acc[1][1]);
      acc[1][2] = fmaf(av.y, bv.z, acc[1][2]); acc[1][3] = fmaf(av.y, bv.w, acc[1][3]);
    }
    __syncthreads();
  }

  float4 bvv = *(const float4*)&bias[bn + (tx << 2)];
#pragma unroll
  for (int r = 0; r < 2; ++r) {
    float4 o;
    o.x = fast_exp2(scale * (acc[r][0] + bvv.x));
    o.y = fast_exp2(scale * (acc[r][1] + bvv.y));
    o.z = fast_exp2(scale * (acc[r][2] + bvv.z));
    o.w = fast_exp2(scale * (acc[r][3] + bvv.w));
    *(float4*)(out + (size_t)(row0 + (ty << 1) + r) * DD + bn + (tx << 2)) = o;
  }
}

// ---------------------------------------------------------------------------
// Fused score + softmax + context + concat + transposed alignment.
// 512 blocks x 512 threads (8 waves), LDS 73.7 KB -> 2 blocks/CU.
// NEW decomposition: lane = d4 (owns d in [4*lane, 4*lane+4)); q fragment
// for 4 rows cached in 16 VGPRs (loaded once from global; no q LDS traffic).
// Wave wv owns j-octet [wv*8, wv*8+8) of each 64-row chunk; each v4 LDS
// read (consecutive-lane, conflict-free) is reused for 4 q-rows.
// d-reduction: 6-step shfl_xor butterfly over the 32 accs; lane 0 writes
// the wave's 32 scores to alg. No cross-wave coupling except barriers.
// Math (inputs Eq, Ev; a = Eq*Ev = exp(2(q+v))):
//   tanh(q+v) = 1 - 2/(1+a);  1/(1+a)+1/(1+b) = (2+a+b)/(1+a+b+ab)
// score = 256 - 2*S,  S = sum_d 1/(1+a_d);  softmax via min-S trick.
// ---------------------------------------------------------------------------
__global__ __launch_bounds__(512, 4) void attn_kernel(
    const float* __restrict__ qp, const float* __restrict__ vp,
    const float* __restrict__ value, const float* __restrict__ query,
    float* __restrict__ out1, float* __restrict__ out2) {
  __shared__ float vs[64][256];   // Ev chunk (lane-consecutive reads: no pad needed)
  __shared__ float alg[4][512];   // raw S, then normalized alignment

  const int t    = threadIdx.x;
  const int lane = t & 63;
  const int wv   = t >> 6;        // 0..7 -> j-octet within chunk
  const int bb   = blockIdx.x & 7;          // batch -> XCD locality
  const int i0   = (blockIdx.x >> 3) << 2;  // first q-row of this block

  // q fragments: lane's d4-quad for the 4 rows (16 VGPRs, global/L2 once)
  const float* qb = qp + (size_t)(bb * TQ + i0) * DD + (lane << 2);
  const float4 q0 = *(const float4*)(qb + 0 * DD);
  const float4 q1 = *(const float4*)(qb + 1 * DD);
  const float4 q2 = *(const float4*)(qb + 2 * DD);
  const float4 q3 = *(const float4*)(qb + 3 * DD);

  const float* vpb = vp + (size_t)bb * TV * DD;
  const int srow = t >> 6;          // staging row base 0..7
  const int scol = (t & 63) << 2;   // staging col (16 B/lane, coalesced)

  for (int c = 0; c < 8; ++c) {
    // stage chunk c (transient regs only -> no scratch)
#pragma unroll
    for (int k = 0; k < 8; ++k) {
      float4 x = *(const float4*)(vpb + (size_t)((c << 6) + (k << 3) + srow) * DD + scol);
      *(float4*)&vs[(k << 3) + srow][scol] = x;
    }
    __syncthreads();

    float acc[4][8];
#pragma unroll
    for (int jj = 0; jj < 8; ++jj) {
      float4 v4 = *(const float4*)&vs[(wv << 3) + jj][lane << 2];
#pragma unroll
      for (int i = 0; i < 4; ++i) {
        const float4 q4 = (i == 0) ? q0 : (i == 1) ? q1 : (i == 2) ? q2 : q3;
        float a0 = q4.x * v4.x, a1 = q4.y * v4.y;
        float a2 = q4.z * v4.z, a3 = q4.w * v4.w;
        float s01 = a0 + a1,   s23 = a2 + a3;
        float d01 = fmaf(a0, a1, s01 + 1.f);
        float d23 = fmaf(a2, a3, s23 + 1.f);
        acc[i][jj] = fmaf(s01 + 2.f, fast_rcp(d01),
                          (s23 + 2.f) * fast_rcp(d23));
      }
    }

    // butterfly over d4-lanes: after 6 steps every lane holds full S
#pragma unroll
    for (int m = 1; m < 64; m <<= 1) {
#pragma unroll
      for (int i = 0; i < 4; ++i)
#pragma unroll
        for (int jj = 0; jj < 8; ++jj)
          acc[i][jj] += __shfl_xor(acc[i][jj], m, 64);
    }
    if (lane == 0) {
      const int jb = (c << 6) + (wv << 3);
#pragma unroll
      for (int i = 0; i < 4; ++i) {
        *(float4*)&alg[i][jb]     = make_float4(acc[i][0], acc[i][1], acc[i][2], acc[i][3]);
        *(float4*)&alg[i][jb + 4] = make_float4(acc[i][4], acc[i][5], acc[i][6], acc[i][7]);
      }
    }
    __syncthreads();  // alg written + all v-reads done before next stage
  }

  // ---- softmax over j: wave wv (<4) owns row wv exclusively ----
  // score = 256 - 2*S -> max(score) <-> min(S); w = exp2(CC*(Smin - S))
  if (wv < 4) {
    float s[8];
#pragma unroll
    for (int c = 0; c < 8; ++c) s[c] = alg[wv][(c << 6) + lane];
    float mn = s[0];
#pragma unroll
    for (int c = 1; c < 8; ++c) mn = fminf(mn, s[c]);
#pragma unroll
    for (int m = 1; m < 64; m <<= 1) mn = fminf(mn, __shfl_xor(mn, m, 64));

    const float CC = 2.8853900817779268f;  // 2*log2(e)
    float p[8];
    float sum = 0.f;
#pragma unroll
    for (int c = 0; c < 8; ++c) { p[c] = fast_exp2(CC * (mn - s[c])); sum += p[c]; }
#pragma unroll
    for (int m = 1; m < 64; m <<= 1) sum += __shfl_xor(sum, m, 64);
    const float inv = fast_rcp(sum);
#pragma unroll
    for (int c = 0; c < 8; ++c) alg[wv][(c << 6) + lane] = p[c] * inv;
  }
  __syncthreads();

  // ---- alignment_t write: out2[b][j][i0..i0+3], one float4 per thread ----
  {
    const int j = t;  // 0..511
    float4 av = make_float4(alg[0][j], alg[1][j], alg[2][j], alg[3][j]);
    *(float4*)(out2 + (size_t)(bb * TV + j) * TQ + i0) = av;
  }

  // ---- context: thread t owns (feature f, row-pair rp) ----
  const int f  = t & 255;
  const int rp = t >> 8;          // 0 or 1 -> rows 2rp, 2rp+1
  float c0 = 0.f, c1 = 0.f;
  const float* vb = value + (size_t)bb * TV * DD;
  const float* a0p = &alg[(rp << 1) + 0][0];
  const float* a1p = &alg[(rp << 1) + 1][0];
#pragma unroll 2
  for (int j = 0; j < TV; j += 4) {
    float v0 = vb[(size_t)(j + 0) * DD + f];
    float v1 = vb[(size_t)(j + 1) * DD + f];
    float v2 = vb[(size_t)(j + 2) * DD + f];
    float v3 = vb[(size_t)(j + 3) * DD + f];
    float4 a0 = *(const float4*)&a0p[j];
    float4 a1 = *(const float4*)&a1p[j];
    c0 += a0.x * v0 + a0.y * v1 + a0.z * v2 + a0.w * v3;
    c1 += a1.x * v0 + a1.y * v1 + a1.z * v2 + a1.w * v3;
  }

  // ---- context-concat output: [ctx | query] per row ----
  const int r0 = (rp << 1), r1 = r0 + 1;
  const float* qg = query + (size_t)(bb * TQ + i0) * DD;
  float* o = out1 + (size_t)(bb * TQ + i0) * (2 * DD);
  o[r0 * 512 + f] = c0; o[r0 * 512 + 256 + f] = qg[r0 * DD + f];
  o[r1 * 512 + f] = c1; o[r1 * 512 + 256 + f] = qg[r1 * DD + f];
}

// ---------------------------------------------------------------------------
extern "C" void kernel_launch(void* const* d_in, const int* in_sizes, int n_in,
                              void* d_out, int out_size, void* d_ws, size_t ws_size,
                              hipStream_t stream) {
  const float* query = (const float*)d_in[0];  // [8,256,256]
  const float* value = (const float*)d_in[1];  // [8,512,256]
  const float* W1    = (const float*)d_in[2];  // [256,256]
  const float* b1    = (const float*)d_in[3];  // [256]
  const float* W2    = (const float*)d_in[4];  // [256,256]
  const float* b2    = (const float*)d_in[5];  // [256]

  float* out1 = (float*)d_out;                     // context concat [8,256,512]
  float* out2 = out1 + (size_t)B_ * TQ * 2 * DD;   // alignment_t   [8,512,256]

  float* qp = (float*)d_ws;                        // Eq: 2048*256 floats
  float* vp = qp + (size_t)B_ * TQ * DD;           // Ev: 4096*256 floats

  const float SC = 2.8853900817779268f;  // 2*log2(e): exp(2x) = exp2(SC*x)

  proj_fused<<<dim3(192, 4), 256, 0, stream>>>(query, value, W1, b1, W2, b2, qp, vp, SC);
  attn_kernel<<<dim3(B_ * (TQ / 4)), 512, 0, stream>>>(qp, vp, value, query, out1, out2);
}

// Round 7
// 147.602 us; speedup vs baseline: 1.3056x; 1.2731x over previous
//
#include <hip/hip_runtime.h>

#define B_  8
#define TQ  256
#define TV  512
#define DD  256

__device__ __forceinline__ float fast_exp2(float x) {
#if __has_builtin(__builtin_amdgcn_exp2f)
  return __builtin_amdgcn_exp2f(x);
#else
  return __exp2f(x);
#endif
}
__device__ __forceinline__ float fast_rcp(float x) {
#if __has_builtin(__builtin_amdgcn_rcpf)
  return __builtin_amdgcn_rcpf(x);
#else
  return 1.0f / x;
#endif
}

// ---------------------------------------------------------------------------
// Fused projections with EXP epilogue:
//   Eq = exp2(SC*(query@W1 + b1)),  Ev = exp2(SC*(value@W2 + b2))
// (unchanged — validated in rounds 5/6)
// ---------------------------------------------------------------------------
__global__ __launch_bounds__(256) void proj_fused(
    const float* __restrict__ query, const float* __restrict__ value,
    const float* __restrict__ W1, const float* __restrict__ b1,
    const float* __restrict__ W2, const float* __restrict__ b2,
    float* __restrict__ qp, float* __restrict__ vp, float scale) {
  __shared__ float As[64][33];  // As[k][m], +1 pad
  __shared__ float Bs[64][64];  // Bs[k][n]
  const int t  = threadIdx.x;
  const int rt = blockIdx.x;
  const int bn = blockIdx.y * 64;

  const float* A; const float* W; const float* bias; float* out; int row0;
  if (rt < 64) { row0 = rt * 32;        A = query; W = W1; bias = b1; out = qp; }
  else         { row0 = (rt - 64) * 32; A = value; W = W2; bias = b2; out = vp; }

  const int tx = t & 15, ty = t >> 4;
  const int arow = t >> 3, acol = (t & 7) << 3;

  float acc[2][4] = {{0.f,0.f,0.f,0.f},{0.f,0.f,0.f,0.f}};

  for (int k0 = 0; k0 < 256; k0 += 64) {
    float4 a0 = *(const float4*)(A + (size_t)(row0 + arow) * DD + k0 + acol);
    float4 a1 = *(const float4*)(A + (size_t)(row0 + arow) * DD + k0 + acol + 4);
    As[acol + 0][arow] = a0.x; As[acol + 1][arow] = a0.y;
    As[acol + 2][arow] = a0.z; As[acol + 3][arow] = a0.w;
    As[acol + 4][arow] = a1.x; As[acol + 5][arow] = a1.y;
    As[acol + 6][arow] = a1.z; As[acol + 7][arow] = a1.w;
#pragma unroll
    for (int k = 0; k < 4; ++k) {
      const int id = (k << 8) + t;
      const int row = id >> 4, col4 = (id & 15) << 2;
      *(float4*)&Bs[row][col4] =
          *(const float4*)(W + (size_t)(k0 + row) * DD + bn + col4);
    }
    __syncthreads();
#pragma unroll 16
    for (int k = 0; k < 64; ++k) {
      float2 av = *(const float2*)&As[k][ty << 1];
      float4 bv = *(const float4*)&Bs[k][tx << 2];
      acc[0][0] = fmaf(av.x, bv.x, acc[0][0]); acc[0][1] = fmaf(av.x, bv.y, acc[0][1]);
      acc[0][2] = fmaf(av.x, bv.z, acc[0][2]); acc[0][3] = fmaf(av.x, bv.w, acc[0][3]);
      acc[1][0] = fmaf(av.y, bv.x, acc[1][0]); acc[1][1] = fmaf(av.y, bv.y, acc[1][1]);
      acc[1][2] = fmaf(av.y, bv.z, acc[1][2]); acc[1][3] = fmaf(av.y, bv.w, acc[1][3]);
    }
    __syncthreads();
  }

  float4 bvv = *(const float4*)&bias[bn + (tx << 2)];
#pragma unroll
  for (int r = 0; r < 2; ++r) {
    float4 o;
    o.x = fast_exp2(scale * (acc[r][0] + bvv.x));
    o.y = fast_exp2(scale * (acc[r][1] + bvv.y));
    o.z = fast_exp2(scale * (acc[r][2] + bvv.z));
    o.w = fast_exp2(scale * (acc[r][3] + bvv.w));
    *(float4*)(out + (size_t)(row0 + (ty << 1) + r) * DD + bn + (tx << 2)) = o;
  }
}

// ---------------------------------------------------------------------------
// Fused score + softmax + context + concat + transposed alignment.
// 512 blocks x 512 threads (8 waves), LDS 73728 B -> 2 blocks/CU.
// lane = j (wave wv owns j = wv*64+lane for the whole kernel); S accumulates
// in acc[4] VGPRs -> NO cross-lane reduction, no shuffles in the hot loop.
// d is chunked (8 chunks x 32 d): vs holds Ev[b][all 512 j][32-d slice],
// row stride 36 (=4 mod 32: measured-conflict-free class). q is read with
// wave-uniform addresses directly from global -> scalar loads, zero q LDS
// traffic. alg[4][512] aliases the dead vs region after the loop.
// Math (inputs Eq, Ev; x = Eq*Ev = exp(2(q+v))), quad-rcp:
//   1/(1+a)+1/(1+b) = (2+a+b)/((1+a)(1+b));  combine two pairs over a
//   common denominator -> 16 VALU + 1 rcp per 4 elems, zero exp2.
// score = 256 - 2*S;  softmax via min-S trick.
// ---------------------------------------------------------------------------
__global__ __launch_bounds__(512, 4) void attn_kernel(
    const float* __restrict__ qp, const float* __restrict__ vp,
    const float* __restrict__ value, const float* __restrict__ query,
    float* __restrict__ out1, float* __restrict__ out2) {
  __shared__ float vs[512 * 36];  // 73728 B; aliased as alg[4][512] after loop
  float* alg = vs;                // alg[i*512 + j]

  const int t    = threadIdx.x;
  const int lane = t & 63;
  const int wv   = t >> 6;        // 0..7
  const int bb   = blockIdx.x & 7;          // batch -> XCD locality
  const int i0   = (blockIdx.x >> 3) << 2;  // first q-row of this block
  const int jrow = (wv << 6) + lane;        // this lane's j (fixed)

  const float* vpb = vp + (size_t)bb * TV * DD;
  const float* qb  = qp + (size_t)(bb * TQ + i0) * DD;  // wave-uniform reads

  const int j0   = t >> 3;        // staging: row within 64-row group
  const int col4 = (t & 7) << 2;  // staging: d-col (floats)

  float acc[4] = {0.f, 0.f, 0.f, 0.f};

#pragma unroll 1
  for (int dc = 0; dc < 8; ++dc) {
    const int dbase = dc << 5;  // 32 d's per chunk
    // stage Ev[b][j][dbase..dbase+32) for all 512 j (transient regs only)
#pragma unroll
    for (int k = 0; k < 8; ++k) {
      const int j = (k << 6) + j0;
      float4 x = *(const float4*)(vpb + (size_t)j * DD + dbase + col4);
      *(float4*)&vs[j * 36 + col4] = x;
    }
    __syncthreads();

#pragma unroll
    for (int d4 = 0; d4 < 8; ++d4) {
      float4 v4 = *(const float4*)&vs[jrow * 36 + (d4 << 2)];
#pragma unroll
      for (int i = 0; i < 4; ++i) {
        // wave-uniform address -> scalar load path (SMEM), not LDS
        float4 q4 = *(const float4*)(qb + i * DD + dbase + (d4 << 2));
        float a = q4.x * v4.x, b = q4.y * v4.y;
        float c = q4.z * v4.z, d = q4.w * v4.w;
        float sab = a + b,  scd = c + d;
        float Q1 = fmaf(a, b, sab + 1.f);   // (1+a)(1+b)
        float Q2 = fmaf(c, d, scd + 1.f);   // (1+c)(1+d)
        float P1 = sab + 2.f, P2 = scd + 2.f;
        float N  = fmaf(P2, Q1, P1 * Q2);
        acc[i] = fmaf(N, fast_rcp(Q1 * Q2), acc[i]);
      }
    }
    __syncthreads();  // all v-reads done before next stage overwrites
  }

  // ---- scores -> alg (aliases vs; all chunk reads already fenced) ----
#pragma unroll
  for (int i = 0; i < 4; ++i) alg[(i << 9) + jrow] = acc[i];
  __syncthreads();

  // ---- softmax over j: wave wv (<4) owns row wv exclusively ----
  // score = 256 - 2*S -> max(score) <-> min(S); w = exp2(CC*(Smin - S))
  if (wv < 4) {
    float s[8];
#pragma unroll
    for (int c = 0; c < 8; ++c) s[c] = alg[(wv << 9) + (c << 6) + lane];
    float mn = s[0];
#pragma unroll
    for (int c = 1; c < 8; ++c) mn = fminf(mn, s[c]);
#pragma unroll
    for (int m = 1; m < 64; m <<= 1) mn = fminf(mn, __shfl_xor(mn, m, 64));

    const float CC = 2.8853900817779268f;  // 2*log2(e)
    float p[8];
    float sum = 0.f;
#pragma unroll
    for (int c = 0; c < 8; ++c) { p[c] = fast_exp2(CC * (mn - s[c])); sum += p[c]; }
#pragma unroll
    for (int m = 1; m < 64; m <<= 1) sum += __shfl_xor(sum, m, 64);
    const float inv = fast_rcp(sum);
#pragma unroll
    for (int c = 0; c < 8; ++c) alg[(wv << 9) + (c << 6) + lane] = p[c] * inv;
  }
  __syncthreads();

  // ---- alignment_t write: out2[b][j][i0..i0+3], one float4 per thread ----
  {
    const int j = t;  // 0..511
    float4 av = make_float4(alg[j], alg[512 + j], alg[1024 + j], alg[1536 + j]);
    *(float4*)(out2 + (size_t)(bb * TV + j) * TQ + i0) = av;
  }

  // ---- context: thread t owns (feature f, row-pair rp) ----
  const int f  = t & 255;
  const int rp = t >> 8;          // 0 or 1 -> rows 2rp, 2rp+1
  float c0 = 0.f, c1 = 0.f;
  const float* vb = value + (size_t)bb * TV * DD;
  const float* a0p = &alg[((rp << 1) + 0) << 9];
  const float* a1p = &alg[((rp << 1) + 1) << 9];
#pragma unroll 2
  for (int j = 0; j < TV; j += 4) {
    float v0 = vb[(size_t)(j + 0) * DD + f];
    float v1 = vb[(size_t)(j + 1) * DD + f];
    float v2 = vb[(size_t)(j + 2) * DD + f];
    float v3 = vb[(size_t)(j + 3) * DD + f];
    float4 a0 = *(const float4*)&a0p[j];
    float4 a1 = *(const float4*)&a1p[j];
    c0 += a0.x * v0 + a0.y * v1 + a0.z * v2 + a0.w * v3;
    c1 += a1.x * v0 + a1.y * v1 + a1.z * v2 + a1.w * v3;
  }

  // ---- context-concat output: [ctx | query] per row ----
  const int r0 = (rp << 1), r1 = r0 + 1;
  const float* qg = query + (size_t)(bb * TQ + i0) * DD;
  float* o = out1 + (size_t)(bb * TQ + i0) * (2 * DD);
  o[r0 * 512 + f] = c0; o[r0 * 512 + 256 + f] = qg[r0 * DD + f];
  o[r1 * 512 + f] = c1; o[r1 * 512 + 256 + f] = qg[r1 * DD + f];
}

// ---------------------------------------------------------------------------
extern "C" void kernel_launch(void* const* d_in, const int* in_sizes, int n_in,
                              void* d_out, int out_size, void* d_ws, size_t ws_size,
                              hipStream_t stream) {
  const float* query = (const float*)d_in[0];  // [8,256,256]
  const float* value = (const float*)d_in[1];  // [8,512,256]
  const float* W1    = (const float*)d_in[2];  // [256,256]
  const float* b1    = (const float*)d_in[3];  // [256]
  const float* W2    = (const float*)d_in[4];  // [256,256]
  const float* b2    = (const float*)d_in[5];  // [256]

  float* out1 = (float*)d_out;                     // context concat [8,256,512]
  float* out2 = out1 + (size_t)B_ * TQ * 2 * DD;   // alignment_t   [8,512,256]

  float* qp = (float*)d_ws;                        // Eq: 2048*256 floats
  float* vp = qp + (size_t)B_ * TQ * DD;           // Ev: 4096*256 floats

  const float SC = 2.8853900817779268f;  // 2*log2(e): exp(2x) = exp2(SC*x)

  proj_fused<<<dim3(192, 4), 256, 0, stream>>>(query, value, W1, b1, W2, b2, qp, vp, SC);
  attn_kernel<<<dim3(B_ * (TQ / 4)), 512, 0, stream>>>(qp, vp, value, query, out1, out2);
}